// Round 3
// baseline (1016.576 us; speedup 1.0000x reference)
//
#include <hip/hip_runtime.h>

#define B_   16
#define NH   12
#define NTOK 576
#define HD   64
#define CH   768
#define NELEM (B_*NH*NTOK*HD)   // 7,077,888 floats per q/k/v buffer

// ---------------------------------------------------------------------------
// K1: qkv[b,n,j] = sum_c x[b,c,n] * w_qkv[j,c];  write q/k/v as [b,h,n,d] fp32
// Tile: BM=64 (n) x BN=128 (j) x BK=16, 256 threads, 4x8 microtile.
// Grid: (18 j-tiles, 9 n-tiles, 16 b) -- all exact, no bounds checks.
// ---------------------------------------------------------------------------
__global__ __launch_bounds__(256) void qkv_gemm(const float* __restrict__ x,
    const float* __restrict__ w, float* __restrict__ q, float* __restrict__ k,
    float* __restrict__ v)
{
    __shared__ float As[16][64];    // [c][n]
    __shared__ float Bs[16][132];   // [c][j] padded (132*4B = 16B multiple)
    const int tid = threadIdx.x;
    const int b  = blockIdx.z;
    const int n0 = blockIdx.y << 6;
    const int j0 = blockIdx.x << 7;
    const int tm = tid >> 4, tn = tid & 15;

    const int la_c = tid >> 4;          // 0..15
    const int la_n = (tid & 15) << 2;   // 0..60
    const int lb_j = tid >> 1;          // 0..127
    const int lb_c = (tid & 1) << 3;    // 0,8

    const float* xa = x + ((size_t)b * CH) * NTOK + n0 + la_n;
    const float* wb = w + (size_t)(j0 + lb_j) * CH + lb_c;

    float acc[4][8];
    #pragma unroll
    for (int m = 0; m < 4; m++)
        #pragma unroll
        for (int j = 0; j < 8; j++) acc[m][j] = 0.f;

    for (int c0 = 0; c0 < CH; c0 += 16) {
        const float4 av = *(const float4*)(xa + (size_t)(c0 + la_c) * NTOK);
        const float4 w0 = *(const float4*)(wb + c0);
        const float4 w1 = *(const float4*)(wb + c0 + 4);
        __syncthreads();
        *(float4*)&As[la_c][la_n] = av;
        Bs[lb_c+0][lb_j] = w0.x; Bs[lb_c+1][lb_j] = w0.y;
        Bs[lb_c+2][lb_j] = w0.z; Bs[lb_c+3][lb_j] = w0.w;
        Bs[lb_c+4][lb_j] = w1.x; Bs[lb_c+5][lb_j] = w1.y;
        Bs[lb_c+6][lb_j] = w1.z; Bs[lb_c+7][lb_j] = w1.w;
        __syncthreads();
        #pragma unroll
        for (int kk = 0; kk < 16; kk++) {
            const float4 a  = *(const float4*)&As[kk][tm << 2];
            const float4 p0 = *(const float4*)&Bs[kk][tn << 3];
            const float4 p1 = *(const float4*)&Bs[kk][(tn << 3) + 4];
            const float am[4] = {a.x, a.y, a.z, a.w};
            const float bj[8] = {p0.x,p0.y,p0.z,p0.w,p1.x,p1.y,p1.z,p1.w};
            #pragma unroll
            for (int m = 0; m < 4; m++)
                #pragma unroll
                for (int j = 0; j < 8; j++)
                    acc[m][j] = fmaf(am[m], bj[j], acc[m][j]);
        }
    }

    // j-tile (128 wide) lies entirely inside one of {q,k,v} (768 each)
    const int which = j0 / CH;
    float* dst = (which == 0) ? q : (which == 1) ? k : v;
    const int jc = (j0 % CH) + (tn << 3);   // column within section
    const int h = jc >> 6;
    const int d = jc & 63;                  // 8 consecutive d, same head
    #pragma unroll
    for (int mm = 0; mm < 4; mm++) {
        const int n = n0 + (tm << 2) + mm;
        float* o = dst + ((((size_t)b * NH + h) * NTOK + n) << 6) + d;
        *(float4*)(o)     = make_float4(acc[mm][0], acc[mm][1], acc[mm][2], acc[mm][3]);
        *(float4*)(o + 4) = make_float4(acc[mm][4], acc[mm][5], acc[mm][6], acc[mm][7]);
    }
}

// ---------------------------------------------------------------------------
// K2: per (b,h): c = mean|q| * mean|k| * 0.125 ; pack sign masks; quantize v
// in place (per-column absmax over n, 8-bit symmetric).  192 blocks x 256.
// ---------------------------------------------------------------------------
__global__ __launch_bounds__(256) void prep(const float* __restrict__ q,
    const float* __restrict__ k, float* __restrict__ v,
    unsigned long long* __restrict__ qm, unsigned long long* __restrict__ km,
    float* __restrict__ cs)
{
    const int bh  = blockIdx.x;
    const int tid = threadIdx.x;
    const size_t base = (size_t)bh * (NTOK * HD);
    const float* qb = q + base;
    const float* kb = k + base;
    float* vb = v + base;

    __shared__ float r1[256], r2[256], vm[256];
    __shared__ float svs[64];

    float sq = 0.f, sk = 0.f;
    for (int i = tid; i < NTOK * HD; i += 256) {
        sq += fabsf(qb[i]);
        sk += fabsf(kb[i]);
    }
    r1[tid] = sq; r2[tid] = sk;

    float m = 0.f;
    const int d = tid & 63;
    for (int n = tid >> 6; n < NTOK; n += 4)
        m = fmaxf(m, fabsf(vb[n * HD + d]));
    vm[tid] = m;
    __syncthreads();

    for (int s = 128; s > 0; s >>= 1) {
        if (tid < s) { r1[tid] += r1[tid + s]; r2[tid] += r2[tid + s]; }
        __syncthreads();
    }
    if (tid == 0) {
        const float msq = r1[0] * (1.f / (NTOK * HD));
        const float msk = r2[0] * (1.f / (NTOK * HD));
        cs[bh] = msq * msk * 0.125f;
    }
    if (tid < 64) {
        const float mm = fmaxf(fmaxf(vm[tid], vm[tid + 64]),
                               fmaxf(vm[tid + 128], vm[tid + 192]));
        svs[tid] = 127.f / (mm + 1e-6f);
    }
    __syncthreads();

    for (int i = tid; i < NTOK * HD; i += 256) {
        const float s = svs[i & 63];
        vb[i] = rintf(vb[i] * s) / (s + 1e-6f);   // matches _quantize_v fwd
    }

    const int wave = tid >> 6, lane = tid & 63;
    for (int n = wave; n < NTOK; n += 4) {
        const unsigned long long mq = __ballot(qb[n * HD + lane] >= 0.f);
        const unsigned long long mk = __ballot(kb[n * HD + lane] >= 0.f);
        if (lane == 0) { qm[bh * NTOK + n] = mq; km[bh * NTOK + n] = mk; }
    }
}

// ---------------------------------------------------------------------------
// K3: fused binary attention.  One block = (b,h, 64-row n-tile), 256 threads.
// logits = c*(64-2*popc); softmax without max-sub (|logit|<=64c ~ 1.6, safe);
// p_q = rint(p*255)/255; out = p_q @ v_q  via 64x64 LDS tiles.
// Writes pre[b,n,h*64+d] into the (recycled) q buffer.
// ---------------------------------------------------------------------------
__global__ __launch_bounds__(256) void attn_kernel(
    const unsigned long long* __restrict__ qm,
    const unsigned long long* __restrict__ km,
    const float* __restrict__ v, const float* __restrict__ cs,
    float* __restrict__ pre)
{
    const int tid = threadIdx.x;
    const int t0 = blockIdx.x << 6;
    const int h  = blockIdx.y;
    const int b  = blockIdx.z;
    const int bh = b * NH + h;

    __shared__ unsigned long long kml[NTOK];
    __shared__ unsigned long long qml[64];
    __shared__ float rs[64];
    __shared__ float Ps[64][65];   // +1 pad: kills 16-way conflict on column reads
    __shared__ float Vs[64][64];

    for (int i = tid; i < NTOK; i += 256) kml[i] = km[(size_t)bh * NTOK + i];
    if (tid < 64) qml[tid] = qm[(size_t)bh * NTOK + t0 + tid];
    const float c = cs[bh];
    __syncthreads();

    // Phase A: row sums (wave per row, 16 rows per wave)
    const int wave = tid >> 6, lane = tid & 63;
    for (int r = wave; r < 64; r += 4) {
        const unsigned long long qq = qml[r];
        float s = 0.f;
        for (int m = lane; m < NTOK; m += 64) {
            const int pc = __popcll(qq ^ kml[m]);
            s += __expf(c * (float)(64 - 2 * pc));
        }
        #pragma unroll
        for (int off = 32; off; off >>= 1) s += __shfl_xor(s, off, 64);
        if (lane == 0) rs[r] = 1.f / s;
    }

    // Phase B: PV accumulation over 9 m-chunks of 64
    float acc[16];
    #pragma unroll
    for (int i = 0; i < 16; i++) acc[i] = 0.f;
    const int r  = tid >> 2;
    const int dg = (tid & 3) << 4;
    const float* vb = v + (size_t)bh * (NTOK * HD);

    for (int m0 = 0; m0 < NTOK; m0 += 64) {
        __syncthreads();
        #pragma unroll
        for (int i = 0; i < 16; i++) {
            const int idx = tid + (i << 8);
            const int rr = idx >> 6, mm = idx & 63;
            const int pc = __popcll(qml[rr] ^ kml[m0 + mm]);
            const float p = __expf(c * (float)(64 - 2 * pc)) * rs[rr];
            Ps[rr][mm] = rintf(p * 255.f) * (1.f / 255.f);
        }
        #pragma unroll
        for (int i = 0; i < 4; i++) {
            const int idx = tid + (i << 8);
            const int mm = idx >> 4, d4 = (idx & 15) << 2;
            *(float4*)&Vs[mm][d4] = *(const float4*)&vb[(m0 + mm) * HD + d4];
        }
        __syncthreads();
        #pragma unroll 8
        for (int mm = 0; mm < 64; mm++) {
            const float p = Ps[r][mm];
            const float* vr = &Vs[mm][dg];
            const float4 v0 = *(const float4*)(vr);
            const float4 v1 = *(const float4*)(vr + 4);
            const float4 v2 = *(const float4*)(vr + 8);
            const float4 v3 = *(const float4*)(vr + 12);
            acc[0]  = fmaf(p, v0.x, acc[0]);  acc[1]  = fmaf(p, v0.y, acc[1]);
            acc[2]  = fmaf(p, v0.z, acc[2]);  acc[3]  = fmaf(p, v0.w, acc[3]);
            acc[4]  = fmaf(p, v1.x, acc[4]);  acc[5]  = fmaf(p, v1.y, acc[5]);
            acc[6]  = fmaf(p, v1.z, acc[6]);  acc[7]  = fmaf(p, v1.w, acc[7]);
            acc[8]  = fmaf(p, v2.x, acc[8]);  acc[9]  = fmaf(p, v2.y, acc[9]);
            acc[10] = fmaf(p, v2.z, acc[10]); acc[11] = fmaf(p, v2.w, acc[11]);
            acc[12] = fmaf(p, v3.x, acc[12]); acc[13] = fmaf(p, v3.y, acc[13]);
            acc[14] = fmaf(p, v3.z, acc[14]); acc[15] = fmaf(p, v3.w, acc[15]);
        }
    }

    float* o = pre + ((size_t)b * NTOK + t0 + r) * CH + h * HD + dg;
    *(float4*)(o)      = make_float4(acc[0],  acc[1],  acc[2],  acc[3]);
    *(float4*)(o + 4)  = make_float4(acc[4],  acc[5],  acc[6],  acc[7]);
    *(float4*)(o + 8)  = make_float4(acc[8],  acc[9],  acc[10], acc[11]);
    *(float4*)(o + 12) = make_float4(acc[12], acc[13], acc[14], acc[15]);
}

// ---------------------------------------------------------------------------
// K4: out[b,co,n] = sum_j pre[b,n,j]*w_proj[co,j] + bias[co]
// Tile: 128 (co) x 64 (n) x 16, 256 threads, 8x4 microtile. Grid (9,6,16).
// ---------------------------------------------------------------------------
__global__ __launch_bounds__(256) void proj_gemm(const float* __restrict__ pre,
    const float* __restrict__ w, const float* __restrict__ bias,
    float* __restrict__ out)
{
    __shared__ float As[16][132];   // [j][co]
    __shared__ float Bs[16][68];    // [j][n]
    const int tid = threadIdx.x;
    const int b   = blockIdx.z;
    const int co0 = blockIdx.y << 7;
    const int n0  = blockIdx.x << 6;
    const int tm = tid >> 4, tn = tid & 15;

    const int la_co = tid >> 1;         // 0..127
    const int la_j  = (tid & 1) << 3;   // 0,8
    const int lb_n  = tid >> 2;         // 0..63
    const int lb_j  = (tid & 3) << 2;   // 0,4,8,12

    const float* wa = w + (size_t)(co0 + la_co) * CH + la_j;
    const float* pb = pre + ((size_t)b * NTOK + n0 + lb_n) * CH + lb_j;

    float acc[8][4];
    #pragma unroll
    for (int m = 0; m < 8; m++)
        #pragma unroll
        for (int j = 0; j < 4; j++) acc[m][j] = 0.f;

    for (int j0 = 0; j0 < CH; j0 += 16) {
        const float4 a0 = *(const float4*)(wa + j0);
        const float4 a1 = *(const float4*)(wa + j0 + 4);
        const float4 bv = *(const float4*)(pb + j0);
        __syncthreads();
        As[la_j+0][la_co] = a0.x; As[la_j+1][la_co] = a0.y;
        As[la_j+2][la_co] = a0.z; As[la_j+3][la_co] = a0.w;
        As[la_j+4][la_co] = a1.x; As[la_j+5][la_co] = a1.y;
        As[la_j+6][la_co] = a1.z; As[la_j+7][la_co] = a1.w;
        Bs[lb_j+0][lb_n] = bv.x; Bs[lb_j+1][lb_n] = bv.y;
        Bs[lb_j+2][lb_n] = bv.z; Bs[lb_j+3][lb_n] = bv.w;
        __syncthreads();
        #pragma unroll
        for (int kk = 0; kk < 16; kk++) {
            const float4 x0 = *(const float4*)&As[kk][tm << 3];
            const float4 x1 = *(const float4*)&As[kk][(tm << 3) + 4];
            const float4 y  = *(const float4*)&Bs[kk][tn << 2];
            const float am[8] = {x0.x,x0.y,x0.z,x0.w,x1.x,x1.y,x1.z,x1.w};
            const float bj[4] = {y.x,y.y,y.z,y.w};
            #pragma unroll
            for (int m = 0; m < 8; m++)
                #pragma unroll
                for (int j = 0; j < 4; j++)
                    acc[m][j] = fmaf(am[m], bj[j], acc[m][j]);
        }
    }

    #pragma unroll
    for (int i = 0; i < 8; i++) {
        const int co = co0 + (tm << 3) + i;
        const float bi = bias[co];
        const float4 rv = make_float4(acc[i][0] + bi, acc[i][1] + bi,
                                      acc[i][2] + bi, acc[i][3] + bi);
        *(float4*)&out[((size_t)b * CH + co) * NTOK + n0 + (tn << 2)] = rv;
    }
}

// ---------------------------------------------------------------------------
extern "C" void kernel_launch(void* const* d_in, const int* in_sizes, int n_in,
                              void* d_out, int out_size, void* d_ws, size_t ws_size,
                              hipStream_t stream)
{
    (void)in_sizes; (void)n_in; (void)out_size; (void)ws_size;
    const float* x     = (const float*)d_in[0];
    const float* wqkv  = (const float*)d_in[1];
    const float* wproj = (const float*)d_in[2];
    const float* bproj = (const float*)d_in[3];
    float* out = (float*)d_out;

    float* qbuf = (float*)d_ws;
    float* kbuf = qbuf + NELEM;
    float* vbuf = kbuf + NELEM;
    unsigned long long* qmask = (unsigned long long*)(vbuf + NELEM);
    unsigned long long* kmask = qmask + (B_ * NH * NTOK);
    float* cs = (float*)(kmask + (B_ * NH * NTOK));

    qkv_gemm<<<dim3(18, 9, B_), 256, 0, stream>>>(x, wqkv, qbuf, kbuf, vbuf);
    prep<<<dim3(B_ * NH), 256, 0, stream>>>(qbuf, kbuf, vbuf, qmask, kmask, cs);
    // attention output (pre-projection, [B,N,C]) recycles qbuf
    attn_kernel<<<dim3(9, NH, B_), 256, 0, stream>>>(qmask, kmask, vbuf, cs, qbuf);
    proj_gemm<<<dim3(9, 6, B_), 256, 0, stream>>>(qbuf, wproj, bproj, out);
}

// Round 5
// 655.710 us; speedup vs baseline: 1.5503x; 1.5503x over previous
//
#include <hip/hip_runtime.h>
#include <hip/hip_bf16.h>

#define B_   16
#define NH   12
#define NTOK 576
#define HD   64
#define CH   768
#define NELEM (B_*NH*NTOK*HD)   // 7,077,888 floats per q/k/v buffer

typedef short v8s __attribute__((ext_vector_type(8)));
typedef short v4s __attribute__((ext_vector_type(4)));
typedef float v4f __attribute__((ext_vector_type(4)));

// split 4 fp32 into hi/lo bf16 (RN): f = hi + lo + O(2^-18 |f|)
static __device__ __forceinline__ void split4(const float* f, v4s& hi, v4s& lo)
{
    #pragma unroll
    for (int i = 0; i < 4; ++i) {
        __hip_bfloat16 h = __float2bfloat16(f[i]);
        float hf = __bfloat162float(h);
        __hip_bfloat16 l = __float2bfloat16(f[i] - hf);
        hi[i] = __builtin_bit_cast(short, h);
        lo[i] = __builtin_bit_cast(short, l);
    }
}

// ---------------------------------------------------------------------------
// K1: qkv[b,n,j] = sum_c x[b,c,n] * w_qkv[j,c]  via 3-term split-bf16 MFMA.
// Block: 64(n) x 256(j), 4 waves, each wave 64x64. K-step 32, 24 iters.
// ---------------------------------------------------------------------------
__global__ __launch_bounds__(256) void qkv_mfma(const float* __restrict__ x,
    const float* __restrict__ w, float* __restrict__ q, float* __restrict__ k,
    float* __restrict__ v)
{
    __shared__ short Ah[64*40], Al[64*40];
    __shared__ short Bh[256*40], Bl[256*40];
    const int tid = threadIdx.x;
    int g = blockIdx.x;
    g = (g & 7) * 162 + (g >> 3);        // bijective: 1296 = 8*162
    const int b  = g / 81;
    const int rr = g % 81;
    const int jb = rr / 9;               // j-block (0..8), 256 wide
    const int mb = rr % 9;               // n-block (0..8), 64 wide (fastest)
    const int n0 = mb * 64;
    const int j0 = jb * 256;
    const int lane = tid & 63, wv = tid >> 6;

    const int cq  = tid & 7;             // k-quad within 32-k tile
    const int rw0 = tid >> 3;            // 0..31 row seed

    const float* xb  = x + (size_t)b * CH * NTOK + n0;
    const float* wbp = w + (size_t)j0 * CH;

    float areg[2][4];
    float breg[8][4];

    #pragma unroll
    for (int s = 0; s < 2; ++s) {
        const int nl = rw0 + 32*s;
        #pragma unroll
        for (int i = 0; i < 4; ++i)
            areg[s][i] = xb[(size_t)(cq*4 + i) * NTOK + nl];
    }
    #pragma unroll
    for (int s = 0; s < 8; ++s) {
        const int jl = rw0 + 32*s;
        const float4 t = *(const float4*)(wbp + (size_t)jl * CH + cq*4);
        breg[s][0]=t.x; breg[s][1]=t.y; breg[s][2]=t.z; breg[s][3]=t.w;
    }

    v4f acc[4][4];
    #pragma unroll
    for (int a = 0; a < 4; ++a)
        #pragma unroll
        for (int c = 0; c < 4; ++c) acc[a][c] = (v4f){0.f,0.f,0.f,0.f};

    for (int it = 0; it < 24; ++it) {
        __syncthreads();
        #pragma unroll
        for (int s = 0; s < 2; ++s) {
            v4s hi, lo; split4(areg[s], hi, lo);
            const int nl = rw0 + 32*s;
            *(v4s*)&Ah[nl*40 + cq*4] = hi;
            *(v4s*)&Al[nl*40 + cq*4] = lo;
        }
        #pragma unroll
        for (int s = 0; s < 8; ++s) {
            v4s hi, lo; split4(breg[s], hi, lo);
            const int jl = rw0 + 32*s;
            *(v4s*)&Bh[jl*40 + cq*4] = hi;
            *(v4s*)&Bl[jl*40 + cq*4] = lo;
        }
        __syncthreads();
        if (it < 23) {                             // prefetch next tile
            const int c0 = (it + 1) * 32;
            #pragma unroll
            for (int s = 0; s < 2; ++s) {
                const int nl = rw0 + 32*s;
                #pragma unroll
                for (int i = 0; i < 4; ++i)
                    areg[s][i] = xb[(size_t)(c0 + cq*4 + i) * NTOK + nl];
            }
            #pragma unroll
            for (int s = 0; s < 8; ++s) {
                const int jl = rw0 + 32*s;
                const float4 t = *(const float4*)(wbp + (size_t)jl * CH + c0 + cq*4);
                breg[s][0]=t.x; breg[s][1]=t.y; breg[s][2]=t.z; breg[s][3]=t.w;
            }
        }
        const int krow = lane & 15;
        const int k0   = (lane >> 4) * 8;
        v8s ah[4], al2[4], bh[4], bl[4];
        #pragma unroll
        for (int mt = 0; mt < 4; ++mt) {
            ah[mt]  = *(v8s*)&Ah[(mt*16 + krow)*40 + k0];
            al2[mt] = *(v8s*)&Al[(mt*16 + krow)*40 + k0];
        }
        #pragma unroll
        for (int jt = 0; jt < 4; ++jt) {
            bh[jt] = *(v8s*)&Bh[(wv*64 + jt*16 + krow)*40 + k0];
            bl[jt] = *(v8s*)&Bl[(wv*64 + jt*16 + krow)*40 + k0];
        }
        #pragma unroll
        for (int mt = 0; mt < 4; ++mt)
            #pragma unroll
            for (int jt = 0; jt < 4; ++jt) {
                acc[mt][jt] = __builtin_amdgcn_mfma_f32_16x16x32_bf16(ah[mt],  bh[jt], acc[mt][jt], 0, 0, 0);
                acc[mt][jt] = __builtin_amdgcn_mfma_f32_16x16x32_bf16(ah[mt],  bl[jt], acc[mt][jt], 0, 0, 0);
                acc[mt][jt] = __builtin_amdgcn_mfma_f32_16x16x32_bf16(al2[mt], bh[jt], acc[mt][jt], 0, 0, 0);
            }
    }

    const int sec = jb / 3;                       // block entirely in q|k|v
    float* dst = (sec == 0) ? q : (sec == 1) ? k : v;
    const int h    = (jb % 3) * 4 + wv;
    const int col  = lane & 15;
    const int row4 = (lane >> 4) * 4;
    #pragma unroll
    for (int mt = 0; mt < 4; ++mt)
        #pragma unroll
        for (int jt = 0; jt < 4; ++jt) {
            const int dd = jt*16 + col;
            float* o = dst + (((size_t)b*NH + h)*NTOK + n0 + mt*16 + row4) * HD + dd;
            #pragma unroll
            for (int rg = 0; rg < 4; ++rg)
                o[(size_t)rg * HD] = acc[mt][jt][rg];
        }
}

// ---------------------------------------------------------------------------
// K2: per (b,h): c = mean|q|*mean|k|*0.125; sign masks; v 8-bit quant.
// Borderline (|val| < 1e-4) masks recomputed with a STRICT SEQUENTIAL fp32
// fmaf chain over c (bit-identical to round-3's passing fp32 GEMM order).
// ---------------------------------------------------------------------------
__global__ __launch_bounds__(256) void prep(const float* __restrict__ q,
    const float* __restrict__ k, float* __restrict__ v,
    unsigned long long* __restrict__ qm, unsigned long long* __restrict__ km,
    float* __restrict__ cs, const float* __restrict__ x,
    const float* __restrict__ wqkv)
{
    const int bh  = blockIdx.x;
    const int tid = threadIdx.x;
    const int b   = bh / NH;
    const int h   = bh % NH;
    const size_t base = (size_t)bh * (NTOK * HD);
    const float* qb = q + base;
    const float* kb = k + base;
    float* vb = v + base;

    __shared__ float r1[256], r2[256], vm[256];
    __shared__ float svs[64];
    __shared__ unsigned qml32[2*NTOK], kml32[2*NTOK];
    __shared__ int fixq[512];
    __shared__ int fixn;
    if (tid == 0) fixn = 0;

    float sq = 0.f, sk = 0.f;
    for (int i = tid; i < NTOK * HD; i += 256) {
        sq += fabsf(qb[i]);
        sk += fabsf(kb[i]);
    }
    r1[tid] = sq; r2[tid] = sk;

    float m = 0.f;
    const int d = tid & 63;
    for (int n = tid >> 6; n < NTOK; n += 4)
        m = fmaxf(m, fabsf(vb[n * HD + d]));
    vm[tid] = m;
    __syncthreads();

    for (int s = 128; s > 0; s >>= 1) {
        if (tid < s) { r1[tid] += r1[tid + s]; r2[tid] += r2[tid + s]; }
        __syncthreads();
    }
    if (tid == 0) {
        const float msq = r1[0] * (1.f / (NTOK * HD));
        const float msk = r2[0] * (1.f / (NTOK * HD));
        cs[bh] = msq * msk * 0.125f;
    }
    if (tid < 64) {
        const float mm = fmaxf(fmaxf(vm[tid], vm[tid + 64]),
                               fmaxf(vm[tid + 128], vm[tid + 192]));
        svs[tid] = 127.f / (mm + 1e-6f);
    }
    __syncthreads();

    const int wv = tid >> 6, lane = tid & 63;
    for (int n = wv; n < NTOK; n += 4) {
        const float qv = qb[n * HD + lane];
        const float kv = kb[n * HD + lane];
        const unsigned long long mq = __ballot(qv >= 0.f);
        const unsigned long long mk = __ballot(kv >= 0.f);
        if (lane == 0) {
            qml32[2*n] = (unsigned)mq; qml32[2*n+1] = (unsigned)(mq >> 32);
            kml32[2*n] = (unsigned)mk; kml32[2*n+1] = (unsigned)(mk >> 32);
        }
        if (fabsf(qv) < 1e-4f) {
            int s_ = atomicAdd(&fixn, 1);
            if (s_ < 512) fixq[s_] = n | (lane << 10);
        }
        if (fabsf(kv) < 1e-4f) {
            int s_ = atomicAdd(&fixn, 1);
            if (s_ < 512) fixq[s_] = n | (lane << 10) | (1 << 16);
        }
    }
    __syncthreads();

    // per-lane exact recompute, STRICT sequential c order (matches round-3
    // fp32 GEMM rounding exactly: single fmaf chain, ascending c)
    const int nf = min(fixn, 512);
    for (int e = tid; e < nf; e += 256) {
        const int rec = fixq[e];
        const int n   = rec & 1023;
        const int dd  = (rec >> 10) & 63;
        const int isk = (rec >> 16) & 1;
        const int row = isk * CH + h * HD + dd;
        const float* wr = wqkv + (size_t)row * CH;
        const float* xr = x + (size_t)b * CH * NTOK + n;
        float s = 0.f;
        #pragma unroll 8
        for (int c = 0; c < CH; ++c)
            s = fmaf(xr[(size_t)c * NTOK], wr[c], s);
        unsigned* arr = isk ? kml32 : qml32;
        const unsigned bit = 1u << (dd & 31);
        const int idx = 2*n + (dd >> 5);
        if (s >= 0.f) atomicOr(&arr[idx], bit);
        else          atomicAnd(&arr[idx], ~bit);
    }
    __syncthreads();

    for (int n = tid; n < NTOK; n += 256) {
        qm[(size_t)bh*NTOK + n] = (unsigned long long)qml32[2*n] |
                                  ((unsigned long long)qml32[2*n+1] << 32);
        km[(size_t)bh*NTOK + n] = (unsigned long long)kml32[2*n] |
                                  ((unsigned long long)kml32[2*n+1] << 32);
    }

    for (int i = tid; i < NTOK * HD; i += 256) {
        const float s = svs[i & 63];
        vb[i] = rintf(vb[i] * s) / (s + 1e-6f);   // matches _quantize_v fwd
    }
}

// ---------------------------------------------------------------------------
// K3: fused binary attention (unchanged from passing round-3 version).
// ---------------------------------------------------------------------------
__global__ __launch_bounds__(256) void attn_kernel(
    const unsigned long long* __restrict__ qm,
    const unsigned long long* __restrict__ km,
    const float* __restrict__ v, const float* __restrict__ cs,
    float* __restrict__ pre)
{
    const int tid = threadIdx.x;
    const int t0 = blockIdx.x << 6;
    const int h  = blockIdx.y;
    const int b  = blockIdx.z;
    const int bh = b * NH + h;

    __shared__ unsigned long long kml[NTOK];
    __shared__ unsigned long long qml[64];
    __shared__ float rs[64];
    __shared__ float Ps[64][65];
    __shared__ float Vs[64][64];

    for (int i = tid; i < NTOK; i += 256) kml[i] = km[(size_t)bh * NTOK + i];
    if (tid < 64) qml[tid] = qm[(size_t)bh * NTOK + t0 + tid];
    const float c = cs[bh];
    __syncthreads();

    const int wave = tid >> 6, lane = tid & 63;
    for (int r = wave; r < 64; r += 4) {
        const unsigned long long qq = qml[r];
        float s = 0.f;
        for (int m = lane; m < NTOK; m += 64) {
            const int pc = __popcll(qq ^ kml[m]);
            s += __expf(c * (float)(64 - 2 * pc));
        }
        #pragma unroll
        for (int off = 32; off; off >>= 1) s += __shfl_xor(s, off, 64);
        if (lane == 0) rs[r] = 1.f / s;
    }

    float acc[16];
    #pragma unroll
    for (int i = 0; i < 16; i++) acc[i] = 0.f;
    const int r  = tid >> 2;
    const int dg = (tid & 3) << 4;
    const float* vb = v + (size_t)bh * (NTOK * HD);

    for (int m0 = 0; m0 < NTOK; m0 += 64) {
        __syncthreads();
        #pragma unroll
        for (int i = 0; i < 16; i++) {
            const int idx = tid + (i << 8);
            const int rr = idx >> 6, mm = idx & 63;
            const int pc = __popcll(qml[rr] ^ kml[m0 + mm]);
            const float p = __expf(c * (float)(64 - 2 * pc)) * rs[rr];
            Ps[rr][mm] = rintf(p * 255.f) * (1.f / 255.f);
        }
        #pragma unroll
        for (int i = 0; i < 4; i++) {
            const int idx = tid + (i << 8);
            const int mm = idx >> 4, d4 = (idx & 15) << 2;
            *(float4*)&Vs[mm][d4] = *(const float4*)&vb[(m0 + mm) * HD + d4];
        }
        __syncthreads();
        #pragma unroll 8
        for (int mm = 0; mm < 64; mm++) {
            const float p = Ps[r][mm];
            const float* vr = &Vs[mm][dg];
            const float4 v0 = *(const float4*)(vr);
            const float4 v1 = *(const float4*)(vr + 4);
            const float4 v2 = *(const float4*)(vr + 8);
            const float4 v3 = *(const float4*)(vr + 12);
            acc[0]  = fmaf(p, v0.x, acc[0]);  acc[1]  = fmaf(p, v0.y, acc[1]);
            acc[2]  = fmaf(p, v0.z, acc[2]);  acc[3]  = fmaf(p, v0.w, acc[3]);
            acc[4]  = fmaf(p, v1.x, acc[4]);  acc[5]  = fmaf(p, v1.y, acc[5]);
            acc[6]  = fmaf(p, v1.z, acc[6]);  acc[7]  = fmaf(p, v1.w, acc[7]);
            acc[8]  = fmaf(p, v2.x, acc[8]);  acc[9]  = fmaf(p, v2.y, acc[9]);
            acc[10] = fmaf(p, v2.z, acc[10]); acc[11] = fmaf(p, v2.w, acc[11]);
            acc[12] = fmaf(p, v3.x, acc[12]); acc[13] = fmaf(p, v3.y, acc[13]);
            acc[14] = fmaf(p, v3.z, acc[14]); acc[15] = fmaf(p, v3.w, acc[15]);
        }
    }

    float* o = pre + ((size_t)b * NTOK + t0 + r) * CH + h * HD + dg;
    *(float4*)(o)      = make_float4(acc[0],  acc[1],  acc[2],  acc[3]);
    *(float4*)(o + 4)  = make_float4(acc[4],  acc[5],  acc[6],  acc[7]);
    *(float4*)(o + 8)  = make_float4(acc[8],  acc[9],  acc[10], acc[11]);
    *(float4*)(o + 12) = make_float4(acc[12], acc[13], acc[14], acc[15]);
}

// ---------------------------------------------------------------------------
// K4: out[b,co,n] = sum_j pre[b,n,j]*w_proj[co,j] + bias[co], split-bf16 MFMA.
// ---------------------------------------------------------------------------
__global__ __launch_bounds__(256) void proj_mfma(const float* __restrict__ pre,
    const float* __restrict__ w, const float* __restrict__ bias,
    float* __restrict__ out)
{
    __shared__ short Awh[256*40], Awl[256*40];
    __shared__ short Bph[64*40],  Bpl[64*40];
    const int tid = threadIdx.x;
    int g = blockIdx.x;
    g = (g & 7) * 54 + (g >> 3);         // bijective: 432 = 8*54
    const int b  = g / 27;
    const int rr = g % 27;
    const int cb = rr / 9;
    const int nb = rr % 9;
    const int co0 = cb * 256;
    const int nn0 = nb * 64;
    const int lane = tid & 63, wv = tid >> 6;
    const int cq  = tid & 7;
    const int rw0 = tid >> 3;

    const float* wp = w + (size_t)co0 * CH;
    const float* pb = pre + ((size_t)b * NTOK + nn0) * CH;

    float areg[8][4];
    float breg[2][4];

    #pragma unroll
    for (int s = 0; s < 8; ++s) {
        const int cl = rw0 + 32*s;
        const float4 t = *(const float4*)(wp + (size_t)cl * CH + cq*4);
        areg[s][0]=t.x; areg[s][1]=t.y; areg[s][2]=t.z; areg[s][3]=t.w;
    }
    #pragma unroll
    for (int s = 0; s < 2; ++s) {
        const int nl = rw0 + 32*s;
        const float4 t = *(const float4*)(pb + (size_t)nl * CH + cq*4);
        breg[s][0]=t.x; breg[s][1]=t.y; breg[s][2]=t.z; breg[s][3]=t.w;
    }

    v4f acc[4][4];
    #pragma unroll
    for (int a = 0; a < 4; ++a)
        #pragma unroll
        for (int c = 0; c < 4; ++c) acc[a][c] = (v4f){0.f,0.f,0.f,0.f};

    for (int it = 0; it < 24; ++it) {
        __syncthreads();
        #pragma unroll
        for (int s = 0; s < 8; ++s) {
            v4s hi, lo; split4(areg[s], hi, lo);
            const int cl = rw0 + 32*s;
            *(v4s*)&Awh[cl*40 + cq*4] = hi;
            *(v4s*)&Awl[cl*40 + cq*4] = lo;
        }
        #pragma unroll
        for (int s = 0; s < 2; ++s) {
            v4s hi, lo; split4(breg[s], hi, lo);
            const int nl = rw0 + 32*s;
            *(v4s*)&Bph[nl*40 + cq*4] = hi;
            *(v4s*)&Bpl[nl*40 + cq*4] = lo;
        }
        __syncthreads();
        if (it < 23) {
            const int k0g = (it + 1) * 32;
            #pragma unroll
            for (int s = 0; s < 8; ++s) {
                const int cl = rw0 + 32*s;
                const float4 t = *(const float4*)(wp + (size_t)cl * CH + k0g + cq*4);
                areg[s][0]=t.x; areg[s][1]=t.y; areg[s][2]=t.z; areg[s][3]=t.w;
            }
            #pragma unroll
            for (int s = 0; s < 2; ++s) {
                const int nl = rw0 + 32*s;
                const float4 t = *(const float4*)(pb + (size_t)nl * CH + k0g + cq*4);
                breg[s][0]=t.x; breg[s][1]=t.y; breg[s][2]=t.z; breg[s][3]=t.w;
            }
        }
        const int krow = lane & 15;
        const int k0   = (lane >> 4) * 8;
        v8s ah[4], al2[4], bh[4], bl[4];
        #pragma unroll
        for (int mt = 0; mt < 4; ++mt) {
            ah[mt]  = *(v8s*)&Awh[(wv*64 + mt*16 + krow)*40 + k0];
            al2[mt] = *(v8s*)&Awl[(wv*64 + mt*16 + krow)*40 + k0];
        }
        #pragma unroll
        for (int jt = 0; jt < 4; ++jt) {
            bh[jt] = *(v8s*)&Bph[(jt*16 + krow)*40 + k0];
            bl[jt] = *(v8s*)&Bpl[(jt*16 + krow)*40 + k0];
        }
        #pragma unroll
        for (int mt = 0; mt < 4; ++mt)
            #pragma unroll
            for (int jt = 0; jt < 4; ++jt) {
                acc[mt][jt] = __builtin_amdgcn_mfma_f32_16x16x32_bf16(ah[mt],  bh[jt], acc[mt][jt], 0, 0, 0);
                acc[mt][jt] = __builtin_amdgcn_mfma_f32_16x16x32_bf16(ah[mt],  bl[jt], acc[mt][jt], 0, 0, 0);
                acc[mt][jt] = __builtin_amdgcn_mfma_f32_16x16x32_bf16(al2[mt], bh[jt], acc[mt][jt], 0, 0, 0);
            }
    }

    const int col  = lane & 15;
    const int row4 = (lane >> 4) * 4;
    #pragma unroll
    for (int mt = 0; mt < 4; ++mt)
        #pragma unroll
        for (int rg = 0; rg < 4; ++rg) {
            const int co = co0 + wv*64 + mt*16 + row4 + rg;
            const float bi = bias[co];
            #pragma unroll
            for (int jt = 0; jt < 4; ++jt)
                out[((size_t)b * CH + co) * NTOK + nn0 + jt*16 + col] =
                    acc[mt][jt][rg] + bi;
        }
}

// ---------------------------------------------------------------------------
extern "C" void kernel_launch(void* const* d_in, const int* in_sizes, int n_in,
                              void* d_out, int out_size, void* d_ws, size_t ws_size,
                              hipStream_t stream)
{
    (void)in_sizes; (void)n_in; (void)out_size; (void)ws_size;
    const float* x     = (const float*)d_in[0];
    const float* wqkv  = (const float*)d_in[1];
    const float* wproj = (const float*)d_in[2];
    const float* bproj = (const float*)d_in[3];
    float* out = (float*)d_out;

    float* qbuf = (float*)d_ws;
    float* kbuf = qbuf + NELEM;
    float* vbuf = kbuf + NELEM;
    unsigned long long* qmask = (unsigned long long*)(vbuf + NELEM);
    unsigned long long* kmask = qmask + (B_ * NH * NTOK);
    float* cs = (float*)(kmask + (B_ * NH * NTOK));

    qkv_mfma<<<dim3(1296), 256, 0, stream>>>(x, wqkv, qbuf, kbuf, vbuf);
    prep<<<dim3(B_ * NH), 256, 0, stream>>>(qbuf, kbuf, vbuf, qmask, kmask, cs,
                                            x, wqkv);
    attn_kernel<<<dim3(9, NH, B_), 256, 0, stream>>>(qmask, kmask, vbuf, cs, qbuf);
    proj_mfma<<<dim3(432), 256, 0, stream>>>(qbuf, wproj, bproj, out);
}

// Round 6
// 504.030 us; speedup vs baseline: 2.0169x; 1.3009x over previous
//
#include <hip/hip_runtime.h>
#include <hip/hip_bf16.h>

#define B_   16
#define NH   12
#define NTOK 576
#define HD   64
#define CH   768
#define NELEM (B_*NH*NTOK*HD)   // 7,077,888 floats per q/k/v buffer
#define VT8STRIDE (NTOK*HD*4)   // 147456 B: per-bh fp32 chunk (vt8 aliases head)

typedef short v8s __attribute__((ext_vector_type(8)));
typedef short v4s __attribute__((ext_vector_type(4)));
typedef float v4f __attribute__((ext_vector_type(4)));
typedef int   v4i __attribute__((ext_vector_type(4)));

// split 4 fp32 into hi/lo bf16 (RN): f = hi + lo + O(2^-18 |f|)
static __device__ __forceinline__ void split4(const float* f, v4s& hi, v4s& lo)
{
    #pragma unroll
    for (int i = 0; i < 4; ++i) {
        __hip_bfloat16 h = __float2bfloat16(f[i]);
        float hf = __bfloat162float(h);
        __hip_bfloat16 l = __float2bfloat16(f[i] - hf);
        hi[i] = __builtin_bit_cast(short, h);
        lo[i] = __builtin_bit_cast(short, l);
    }
}

// ---------------------------------------------------------------------------
// K1: qkv[b,n,j] = sum_c x[b,c,n] * w_qkv[j,c]  via 3-term split-bf16 MFMA.
// (unchanged from round-5 passing version)
// ---------------------------------------------------------------------------
__global__ __launch_bounds__(256) void qkv_mfma(const float* __restrict__ x,
    const float* __restrict__ w, float* __restrict__ q, float* __restrict__ k,
    float* __restrict__ v)
{
    __shared__ short Ah[64*40], Al[64*40];
    __shared__ short Bh[256*40], Bl[256*40];
    const int tid = threadIdx.x;
    int g = blockIdx.x;
    g = (g & 7) * 162 + (g >> 3);        // bijective: 1296 = 8*162
    const int b  = g / 81;
    const int rr = g % 81;
    const int jb = rr / 9;
    const int mb = rr % 9;
    const int n0 = mb * 64;
    const int j0 = jb * 256;
    const int lane = tid & 63, wv = tid >> 6;

    const int cq  = tid & 7;
    const int rw0 = tid >> 3;

    const float* xb  = x + (size_t)b * CH * NTOK + n0;
    const float* wbp = w + (size_t)j0 * CH;

    float areg[2][4];
    float breg[8][4];

    #pragma unroll
    for (int s = 0; s < 2; ++s) {
        const int nl = rw0 + 32*s;
        #pragma unroll
        for (int i = 0; i < 4; ++i)
            areg[s][i] = xb[(size_t)(cq*4 + i) * NTOK + nl];
    }
    #pragma unroll
    for (int s = 0; s < 8; ++s) {
        const int jl = rw0 + 32*s;
        const float4 t = *(const float4*)(wbp + (size_t)jl * CH + cq*4);
        breg[s][0]=t.x; breg[s][1]=t.y; breg[s][2]=t.z; breg[s][3]=t.w;
    }

    v4f acc[4][4];
    #pragma unroll
    for (int a = 0; a < 4; ++a)
        #pragma unroll
        for (int c = 0; c < 4; ++c) acc[a][c] = (v4f){0.f,0.f,0.f,0.f};

    for (int it = 0; it < 24; ++it) {
        __syncthreads();
        #pragma unroll
        for (int s = 0; s < 2; ++s) {
            v4s hi, lo; split4(areg[s], hi, lo);
            const int nl = rw0 + 32*s;
            *(v4s*)&Ah[nl*40 + cq*4] = hi;
            *(v4s*)&Al[nl*40 + cq*4] = lo;
        }
        #pragma unroll
        for (int s = 0; s < 8; ++s) {
            v4s hi, lo; split4(breg[s], hi, lo);
            const int jl = rw0 + 32*s;
            *(v4s*)&Bh[jl*40 + cq*4] = hi;
            *(v4s*)&Bl[jl*40 + cq*4] = lo;
        }
        __syncthreads();
        if (it < 23) {
            const int c0 = (it + 1) * 32;
            #pragma unroll
            for (int s = 0; s < 2; ++s) {
                const int nl = rw0 + 32*s;
                #pragma unroll
                for (int i = 0; i < 4; ++i)
                    areg[s][i] = xb[(size_t)(c0 + cq*4 + i) * NTOK + nl];
            }
            #pragma unroll
            for (int s = 0; s < 8; ++s) {
                const int jl = rw0 + 32*s;
                const float4 t = *(const float4*)(wbp + (size_t)jl * CH + c0 + cq*4);
                breg[s][0]=t.x; breg[s][1]=t.y; breg[s][2]=t.z; breg[s][3]=t.w;
            }
        }
        const int krow = lane & 15;
        const int k0   = (lane >> 4) * 8;
        v8s ah[4], al2[4], bh[4], bl[4];
        #pragma unroll
        for (int mt = 0; mt < 4; ++mt) {
            ah[mt]  = *(v8s*)&Ah[(mt*16 + krow)*40 + k0];
            al2[mt] = *(v8s*)&Al[(mt*16 + krow)*40 + k0];
        }
        #pragma unroll
        for (int jt = 0; jt < 4; ++jt) {
            bh[jt] = *(v8s*)&Bh[(wv*64 + jt*16 + krow)*40 + k0];
            bl[jt] = *(v8s*)&Bl[(wv*64 + jt*16 + krow)*40 + k0];
        }
        #pragma unroll
        for (int mt = 0; mt < 4; ++mt)
            #pragma unroll
            for (int jt = 0; jt < 4; ++jt) {
                acc[mt][jt] = __builtin_amdgcn_mfma_f32_16x16x32_bf16(ah[mt],  bh[jt], acc[mt][jt], 0, 0, 0);
                acc[mt][jt] = __builtin_amdgcn_mfma_f32_16x16x32_bf16(ah[mt],  bl[jt], acc[mt][jt], 0, 0, 0);
                acc[mt][jt] = __builtin_amdgcn_mfma_f32_16x16x32_bf16(al2[mt], bh[jt], acc[mt][jt], 0, 0, 0);
            }
    }

    const int sec = jb / 3;
    float* dst = (sec == 0) ? q : (sec == 1) ? k : v;
    const int h    = (jb % 3) * 4 + wv;
    const int col  = lane & 15;
    const int row4 = (lane >> 4) * 4;
    #pragma unroll
    for (int mt = 0; mt < 4; ++mt)
        #pragma unroll
        for (int jt = 0; jt < 4; ++jt) {
            const int dd = jt*16 + col;
            float* o = dst + (((size_t)b*NH + h)*NTOK + n0 + mt*16 + row4) * HD + dd;
            #pragma unroll
            for (int rg = 0; rg < 4; ++rg)
                o[(size_t)rg * HD] = acc[mt][jt][rg];
        }
}

// ---------------------------------------------------------------------------
// K2: per (b,h): c scalar; sign masks (sequential-fp32 fixup for |val|<1e-4);
// NEW: v quantized to int8, written TRANSPOSED [d][576] into the head of this
// bh's own (dead) fp32-V chunk, plus per-d colsum (i32) and dequant scale.
// ---------------------------------------------------------------------------
__global__ __launch_bounds__(256) void prep(const float* __restrict__ q,
    const float* __restrict__ k, const float* v,
    unsigned long long* __restrict__ qm, unsigned long long* __restrict__ km,
    float* __restrict__ cs, const float* __restrict__ x,
    const float* __restrict__ wqkv, unsigned char* vt8,
    int* __restrict__ colsum_g, float* __restrict__ scale_g)
{
    const int bh  = blockIdx.x;
    const int tid = threadIdx.x;
    const int b   = bh / NH;
    const int h   = bh % NH;
    const size_t base = (size_t)bh * (NTOK * HD);
    const float* qb = q + base;
    const float* kb = k + base;
    const float* vb = v + base;

    __shared__ float r1[256], r2[256], vm[256];
    __shared__ float svs[64];
    __shared__ unsigned qml32[2*NTOK], kml32[2*NTOK];
    __shared__ int fixq[512];
    __shared__ int fixn;
    __shared__ unsigned char vt[64*592];
    __shared__ int csum_s[256];
    if (tid == 0) fixn = 0;

    float sq = 0.f, sk = 0.f;
    for (int i = tid; i < NTOK * HD; i += 256) {
        sq += fabsf(qb[i]);
        sk += fabsf(kb[i]);
    }
    r1[tid] = sq; r2[tid] = sk;

    float m = 0.f;
    const int d = tid & 63;
    for (int n = tid >> 6; n < NTOK; n += 4)
        m = fmaxf(m, fabsf(vb[n * HD + d]));
    vm[tid] = m;
    __syncthreads();

    for (int s = 128; s > 0; s >>= 1) {
        if (tid < s) { r1[tid] += r1[tid + s]; r2[tid] += r2[tid + s]; }
        __syncthreads();
    }
    if (tid == 0) {
        const float msq = r1[0] * (1.f / (NTOK * HD));
        const float msk = r2[0] * (1.f / (NTOK * HD));
        cs[bh] = msq * msk * 0.125f;
    }
    if (tid < 64) {
        const float mm = fmaxf(fmaxf(vm[tid], vm[tid + 64]),
                               fmaxf(vm[tid + 128], vm[tid + 192]));
        svs[tid] = 127.f / (mm + 1e-6f);
    }
    __syncthreads();

    const int wv = tid >> 6, lane = tid & 63;
    for (int n = wv; n < NTOK; n += 4) {
        const float qv = qb[n * HD + lane];
        const float kv = kb[n * HD + lane];
        const unsigned long long mq = __ballot(qv >= 0.f);
        const unsigned long long mk = __ballot(kv >= 0.f);
        if (lane == 0) {
            qml32[2*n] = (unsigned)mq; qml32[2*n+1] = (unsigned)(mq >> 32);
            kml32[2*n] = (unsigned)mk; kml32[2*n+1] = (unsigned)(mk >> 32);
        }
        if (fabsf(qv) < 1e-4f) {
            int s_ = atomicAdd(&fixn, 1);
            if (s_ < 512) fixq[s_] = n | (lane << 10);
        }
        if (fabsf(kv) < 1e-4f) {
            int s_ = atomicAdd(&fixn, 1);
            if (s_ < 512) fixq[s_] = n | (lane << 10) | (1 << 16);
        }
    }

    // v -> int8 transposed in LDS: vt[d][n]
    for (int i = tid; i < NTOK * HD; i += 256) {
        const float s = svs[i & 63];
        const int iq = (int)rintf(vb[i] * s);        // in [-127,127]
        vt[(i & 63) * 592 + (i >> 6)] = (unsigned char)(iq & 255);
    }
    __syncthreads();

    // borderline sign fixup: strict sequential fp32 fmaf chain over c
    const int nf = min(fixn, 512);
    for (int e = tid; e < nf; e += 256) {
        const int rec = fixq[e];
        const int n   = rec & 1023;
        const int dd  = (rec >> 10) & 63;
        const int isk = (rec >> 16) & 1;
        const int row = isk * CH + h * HD + dd;
        const float* wr = wqkv + (size_t)row * CH;
        const float* xr = x + (size_t)b * CH * NTOK + n;
        float s = 0.f;
        #pragma unroll 8
        for (int c = 0; c < CH; ++c)
            s = fmaf(xr[(size_t)c * NTOK], wr[c], s);
        unsigned* arr = isk ? kml32 : qml32;
        const unsigned bit = 1u << (dd & 31);
        const int idx = 2*n + (dd >> 5);
        if (s >= 0.f) atomicOr(&arr[idx], bit);
        else          atomicAnd(&arr[idx], ~bit);
    }

    // per-d column sums of int8 v
    {
        int part = 0;
        for (int n = tid >> 6; n < NTOK; n += 4)
            part += (int)(signed char)vt[(tid & 63) * 592 + n];
        csum_s[tid] = part;
    }
    __syncthreads();

    for (int n = tid; n < NTOK; n += 256) {
        qm[(size_t)bh*NTOK + n] = (unsigned long long)qml32[2*n] |
                                  ((unsigned long long)qml32[2*n+1] << 32);
        km[(size_t)bh*NTOK + n] = (unsigned long long)kml32[2*n] |
                                  ((unsigned long long)kml32[2*n+1] << 32);
    }
    if (tid < 64) {
        colsum_g[bh*64 + tid] = csum_s[tid] + csum_s[tid+64] +
                                csum_s[tid+128] + csum_s[tid+192];
        scale_g[bh*64 + tid] = (1.f/255.f) / (svs[tid] + 1e-6f);
    }
    // write transposed int8 v to global (after ALL vb reads: barrier above)
    {
        unsigned char* dst = vt8 + (size_t)bh * VT8STRIDE;
        #pragma unroll
        for (int t = 0; t < 9; ++t) {
            const int idx = tid + t*256;
            const int row = idx / 36, seg = idx % 36;
            *(int4*)(dst + row*576 + seg*16) = *(const int4*)&vt[row*592 + seg*16];
        }
    }
}

// ---------------------------------------------------------------------------
// K3: fused binary attention via exact int8 MFMA PV + 65-entry exp table.
// One block = (b,h, 64-row n-tile), 4 waves x 16 rows. A-frag (P-128) built
// in registers in MFMA layout; B from LDS int8 V^T (rows padded to 592 B).
// out[n,d] = (acc + 128*colsum[d]) * (1/255)/(s_d+1e-6).
// ---------------------------------------------------------------------------
__global__ __launch_bounds__(256) void attn_i8(
    const unsigned long long* __restrict__ qm,
    const unsigned long long* __restrict__ km,
    const unsigned char* __restrict__ vt8, const float* __restrict__ cs,
    const int* __restrict__ colsum_g, const float* __restrict__ scale_g,
    float* __restrict__ pre)
{
    const int tid = threadIdx.x;
    const int t0 = blockIdx.x << 6;
    const int h  = blockIdx.y;
    const int b  = blockIdx.z;
    const int bh = b * NH + h;

    __shared__ unsigned long long kml[NTOK];   // 4608 B
    __shared__ unsigned long long qml[64];     // 512 B
    __shared__ float rs[64];
    __shared__ float table[65];
    __shared__ unsigned char vt[64*592];       // 37888 B

    for (int i = tid; i < NTOK; i += 256) kml[i] = km[(size_t)bh * NTOK + i];
    if (tid < 64) qml[tid] = qm[(size_t)bh * NTOK + t0 + tid];
    const float c = cs[bh];
    if (tid < 65) table[tid] = __expf(c * (float)(64 - 2 * tid));
    {
        const unsigned char* src = vt8 + (size_t)bh * VT8STRIDE;
        #pragma unroll
        for (int t = 0; t < 9; ++t) {
            const int idx = tid + t*256;
            const int row = idx / 36, seg = idx % 36;
            *(int4*)&vt[row*592 + seg*16] = *(const int4*)(src + row*576 + seg*16);
        }
    }
    __syncthreads();

    // Phase A: row sums (same op order/values as round-5: table[pc]==__expf)
    const int wv = tid >> 6, lane = tid & 63;
    for (int r = wv; r < 64; r += 4) {
        const unsigned long long qq = qml[r];
        float s = 0.f;
        for (int m = lane; m < NTOK; m += 64) {
            const int pc = __popcll(qq ^ kml[m]);
            s += table[pc];
        }
        #pragma unroll
        for (int off = 32; off; off >>= 1) s += __shfl_xor(s, off, 64);
        if (lane == 0) rs[r] = 1.f / s;
    }
    __syncthreads();

    // Phase B: 9 chunks of K=64, 4 MFMA per chunk per wave
    const int row_l = lane & 15;           // A-row / B-col / C-col component
    const int kgrp  = lane >> 4;           // k-group
    const unsigned long long uq = qml[wv*16 + row_l];
    const float rsr = rs[wv*16 + row_l];
    v4i acc[4];
    #pragma unroll
    for (int jt = 0; jt < 4; ++jt) acc[jt] = (v4i){0,0,0,0};

    for (int ch = 0; ch < 9; ++ch) {
        const int mb = ch*64 + kgrp*16;
        int wds[4];
        #pragma unroll
        for (int wq = 0; wq < 4; ++wq) {
            int pk = 0;
            #pragma unroll
            for (int j = 0; j < 4; ++j) {
                const int pc = __popcll(uq ^ kml[mb + wq*4 + j]);
                const float p = table[pc] * rsr;         // same order as r5
                const int iq = (int)rintf(p * 255.f) - 128;
                pk |= (iq & 255) << (8*j);
            }
            wds[wq] = pk;
        }
        v4i a; a[0]=wds[0]; a[1]=wds[1]; a[2]=wds[2]; a[3]=wds[3];
        #pragma unroll
        for (int jt = 0; jt < 4; ++jt) {
            const v4i bfr = *(const v4i*)&vt[(jt*16 + row_l)*592 + mb];
            acc[jt] = __builtin_amdgcn_mfma_i32_16x16x64_i8(a, bfr, acc[jt], 0, 0, 0);
        }
    }

    // epilogue: C/D col=lane&15, row=(lane>>4)*4+reg
    const int rb = kgrp * 4;
    #pragma unroll
    for (int jt = 0; jt < 4; ++jt) {
        const int dd = jt*16 + row_l;
        const int csd = colsum_g[bh*64 + dd];
        const float scd = scale_g[bh*64 + dd];
        #pragma unroll
        for (int rg = 0; rg < 4; ++rg) {
            const int n = t0 + wv*16 + rb + rg;
            pre[((size_t)b * NTOK + n) * CH + h * HD + dd] =
                (float)(acc[jt][rg] + 128 * csd) * scd;
        }
    }
}

// ---------------------------------------------------------------------------
// K4: out[b,co,n] = sum_j pre[b,n,j]*w_proj[co,j] + bias[co], split-bf16 MFMA.
// (unchanged from round-5 passing version)
// ---------------------------------------------------------------------------
__global__ __launch_bounds__(256) void proj_mfma(const float* __restrict__ pre,
    const float* __restrict__ w, const float* __restrict__ bias,
    float* __restrict__ out)
{
    __shared__ short Awh[256*40], Awl[256*40];
    __shared__ short Bph[64*40],  Bpl[64*40];
    const int tid = threadIdx.x;
    int g = blockIdx.x;
    g = (g & 7) * 54 + (g >> 3);         // bijective: 432 = 8*54
    const int b  = g / 27;
    const int rr = g % 27;
    const int cb = rr / 9;
    const int nb = rr % 9;
    const int co0 = cb * 256;
    const int nn0 = nb * 64;
    const int lane = tid & 63, wv = tid >> 6;
    const int cq  = tid & 7;
    const int rw0 = tid >> 3;

    const float* wp = w + (size_t)co0 * CH;
    const float* pb = pre + ((size_t)b * NTOK + nn0) * CH;

    float areg[8][4];
    float breg[2][4];

    #pragma unroll
    for (int s = 0; s < 8; ++s) {
        const int cl = rw0 + 32*s;
        const float4 t = *(const float4*)(wp + (size_t)cl * CH + cq*4);
        areg[s][0]=t.x; areg[s][1]=t.y; areg[s][2]=t.z; areg[s][3]=t.w;
    }
    #pragma unroll
    for (int s = 0; s < 2; ++s) {
        const int nl = rw0 + 32*s;
        const float4 t = *(const float4*)(pb + (size_t)nl * CH + cq*4);
        breg[s][0]=t.x; breg[s][1]=t.y; breg[s][2]=t.z; breg[s][3]=t.w;
    }

    v4f acc[4][4];
    #pragma unroll
    for (int a = 0; a < 4; ++a)
        #pragma unroll
        for (int c = 0; c < 4; ++c) acc[a][c] = (v4f){0.f,0.f,0.f,0.f};

    for (int it = 0; it < 24; ++it) {
        __syncthreads();
        #pragma unroll
        for (int s = 0; s < 8; ++s) {
            v4s hi, lo; split4(areg[s], hi, lo);
            const int cl = rw0 + 32*s;
            *(v4s*)&Awh[cl*40 + cq*4] = hi;
            *(v4s*)&Awl[cl*40 + cq*4] = lo;
        }
        #pragma unroll
        for (int s = 0; s < 2; ++s) {
            v4s hi, lo; split4(breg[s], hi, lo);
            const int nl = rw0 + 32*s;
            *(v4s*)&Bph[nl*40 + cq*4] = hi;
            *(v4s*)&Bpl[nl*40 + cq*4] = lo;
        }
        __syncthreads();
        if (it < 23) {
            const int k0g = (it + 1) * 32;
            #pragma unroll
            for (int s = 0; s < 8; ++s) {
                const int cl = rw0 + 32*s;
                const float4 t = *(const float4*)(wp + (size_t)cl * CH + k0g + cq*4);
                areg[s][0]=t.x; areg[s][1]=t.y; areg[s][2]=t.z; areg[s][3]=t.w;
            }
            #pragma unroll
            for (int s = 0; s < 2; ++s) {
                const int nl = rw0 + 32*s;
                const float4 t = *(const float4*)(pb + (size_t)nl * CH + k0g + cq*4);
                breg[s][0]=t.x; breg[s][1]=t.y; breg[s][2]=t.z; breg[s][3]=t.w;
            }
        }
        const int krow = lane & 15;
        const int k0   = (lane >> 4) * 8;
        v8s ah[4], al2[4], bh[4], bl[4];
        #pragma unroll
        for (int mt = 0; mt < 4; ++mt) {
            ah[mt]  = *(v8s*)&Awh[(wv*64 + mt*16 + krow)*40 + k0];
            al2[mt] = *(v8s*)&Awl[(wv*64 + mt*16 + krow)*40 + k0];
        }
        #pragma unroll
        for (int jt = 0; jt < 4; ++jt) {
            bh[jt] = *(v8s*)&Bph[(jt*16 + krow)*40 + k0];
            bl[jt] = *(v8s*)&Bpl[(jt*16 + krow)*40 + k0];
        }
        #pragma unroll
        for (int mt = 0; mt < 4; ++mt)
            #pragma unroll
            for (int jt = 0; jt < 4; ++jt) {
                acc[mt][jt] = __builtin_amdgcn_mfma_f32_16x16x32_bf16(ah[mt],  bh[jt], acc[mt][jt], 0, 0, 0);
                acc[mt][jt] = __builtin_amdgcn_mfma_f32_16x16x32_bf16(ah[mt],  bl[jt], acc[mt][jt], 0, 0, 0);
                acc[mt][jt] = __builtin_amdgcn_mfma_f32_16x16x32_bf16(al2[mt], bh[jt], acc[mt][jt], 0, 0, 0);
            }
    }

    const int col  = lane & 15;
    const int row4 = (lane >> 4) * 4;
    #pragma unroll
    for (int mt = 0; mt < 4; ++mt)
        #pragma unroll
        for (int rg = 0; rg < 4; ++rg) {
            const int co = co0 + wv*64 + mt*16 + row4 + rg;
            const float bi = bias[co];
            #pragma unroll
            for (int jt = 0; jt < 4; ++jt)
                out[((size_t)b * CH + co) * NTOK + nn0 + jt*16 + col] =
                    acc[mt][jt][rg] + bi;
        }
}

// ---------------------------------------------------------------------------
extern "C" void kernel_launch(void* const* d_in, const int* in_sizes, int n_in,
                              void* d_out, int out_size, void* d_ws, size_t ws_size,
                              hipStream_t stream)
{
    (void)in_sizes; (void)n_in; (void)out_size; (void)ws_size;
    const float* x     = (const float*)d_in[0];
    const float* wqkv  = (const float*)d_in[1];
    const float* wproj = (const float*)d_in[2];
    const float* bproj = (const float*)d_in[3];
    float* out = (float*)d_out;

    float* qbuf = (float*)d_ws;
    float* kbuf = qbuf + NELEM;
    float* vbuf = kbuf + NELEM;
    unsigned long long* qmask = (unsigned long long*)(vbuf + NELEM);
    unsigned long long* kmask = qmask + (B_ * NH * NTOK);
    float* cs = (float*)(kmask + (B_ * NH * NTOK));
    int*   colsum = (int*)(cs + B_ * NH);
    float* scale  = (float*)(colsum + B_ * NH * HD);
    unsigned char* vt8 = (unsigned char*)vbuf;   // per-bh: head of own chunk

    qkv_mfma<<<dim3(1296), 256, 0, stream>>>(x, wqkv, qbuf, kbuf, vbuf);
    prep<<<dim3(B_ * NH), 256, 0, stream>>>(qbuf, kbuf, vbuf, qmask, kmask, cs,
                                            x, wqkv, vt8, colsum, scale);
    attn_i8<<<dim3(9, NH, B_), 256, 0, stream>>>(qmask, kmask, vt8, cs,
                                                 colsum, scale, qbuf);
    proj_mfma<<<dim3(432), 256, 0, stream>>>(qbuf, wproj, bproj, out);
}